// Round 1
// baseline (21.008 us; speedup 1.0000x reference)
//
#include <hip/hip_runtime.h>
#include <hip/hip_bf16.h>

// Reference collapse (KTOP=1): softmax over k=1 == 1, so
//   out[b,c,q] = mean over 4x4 block selected by argmax_j sum_h attn[b,h,l,j]
// where l = low-res cell of pixel q. Only C (d_in[2]) and attn (d_in[4]) used.

// Kernel 1: per (b,l) argmax over j of sum over heads of attn[b,h,l,j].
// grid = 2048 blocks (b*256+l), 256 threads (one per j).
__global__ void ca_argmax_kernel(const float* __restrict__ attn,
                                 int* __restrict__ best) {
    int bl = blockIdx.x;            // b*256 + l
    int b  = bl >> 8;
    int l  = bl & 255;
    int j  = threadIdx.x;           // 0..255

    // attn layout: [8][8][256][256] -> [b][h][l][j]
    const float* base = attn + (((size_t)b * 8) * 256 + l) * 256;
    float s = 0.0f;
#pragma unroll
    for (int h = 0; h < 8; ++h)
        s += base[(size_t)h * 256 * 256 + j];

    __shared__ float sval[256];
    __shared__ int   sidx[256];
    sval[j] = s;
    sidx[j] = j;
    __syncthreads();
#pragma unroll
    for (int off = 128; off > 0; off >>= 1) {
        if (j < off) {
            float v2 = sval[j + off];
            int   i2 = sidx[j + off];
            // prefer larger value; on exact tie prefer lower index (top_k semantics)
            if (v2 > sval[j] || (v2 == sval[j] && i2 < sidx[j])) {
                sval[j] = v2;
                sidx[j] = i2;
            }
        }
        __syncthreads();
    }
    if (j == 0) best[bl] = sidx[0];
}

// Kernel 2: per (b,c) plane. Stage 64x64 plane in LDS, compute 256 cell
// averages, broadcast each to its 4x4 output cell.
// grid = 2048 blocks (b*256+c), 256 threads.
__global__ void ca_resample_kernel(const float* __restrict__ C,
                                   const int* __restrict__ best,
                                   float* __restrict__ out) {
    int bc = blockIdx.x;            // b*256 + c
    int b  = bc >> 8;
    int t  = threadIdx.x;           // 0..255

    __shared__ __align__(16) float plane[64 * 64];
    __shared__ float cellavg[256];

    // Stage full plane: 4096 floats = 1024 float4, 4 per thread, coalesced.
    const float4* src4   = reinterpret_cast<const float4*>(C + (size_t)bc * 4096);
    float4*       plane4 = reinterpret_cast<float4*>(plane);
#pragma unroll
    for (int i = 0; i < 4; ++i)
        plane4[t + i * 256] = src4[t + i * 256];
    __syncthreads();

    // One cell per thread: average the selected 4x4 block.
    {
        int jstar = best[b * 256 + t];
        int tr = (jstar >> 4) << 2;     // top-left row of selected block
        int tc = (jstar & 15) << 2;     // top-left col
        float s = 0.0f;
#pragma unroll
        for (int r = 0; r < 4; ++r) {
            float4 v = *reinterpret_cast<const float4*>(&plane[(tr + r) * 64 + tc]);
            s += (v.x + v.y) + (v.z + v.w);
        }
        cellavg[t] = s * (1.0f / 16.0f);
    }
    __syncthreads();

    // Write output plane: 4 float4 stores per thread, coalesced.
    float4* out4 = reinterpret_cast<float4*>(out + (size_t)bc * 4096);
#pragma unroll
    for (int i = 0; i < 4; ++i) {
        int q4  = i * 1024 + t * 4;     // first pixel index of this float4
        int row = q4 >> 6;
        int col = q4 & 63;
        float v = cellavg[(row >> 2) * 16 + (col >> 2)];
        out4[t + i * 256] = make_float4(v, v, v, v);
    }
}

extern "C" void kernel_launch(void* const* d_in, const int* in_sizes, int n_in,
                              void* d_out, int out_size, void* d_ws, size_t ws_size,
                              hipStream_t stream) {
    const float* C    = (const float*)d_in[2];   // (8,256,64,64)
    const float* attn = (const float*)d_in[4];   // (8,8,256,256)
    float* out = (float*)d_out;                  // (8,256,64,64)
    int* best  = (int*)d_ws;                     // 2048 ints

    ca_argmax_kernel<<<2048, 256, 0, stream>>>(attn, best);
    ca_resample_kernel<<<2048, 256, 0, stream>>>(C, best, out);
}

// Round 3
// 20.680 us; speedup vs baseline: 1.0159x; 1.0159x over previous
//
#include <hip/hip_runtime.h>
#include <hip/hip_bf16.h>
#include <hip/hip_cooperative_groups.h>

namespace cg = cooperative_groups;

// KTOP=1 collapse: out[b,c,pixel q] = mean of the 4x4 block of C[b,c] selected
// by jstar(b,l) = argmax_j sum_h attn[b,h,l,j], where l = low-res cell of q.
//
// Fused cooperative kernel, 2048 blocks (bi = b*256 + i), 256 threads.
// Key trick: blockmean[b,c,j] (mean of 4x4 block j of plane (b,c)) does not
// depend on the argmax, so each block reduces its whole plane to 256 floats
// in LDS BEFORE the grid sync. Phase B is then a 256-float LDS gather.
// LDS = 3 KB/block, VGPR low -> 8 blocks/CU with wide margin.
__global__ __launch_bounds__(256, 8) void ca_fused_kernel(
    const float* __restrict__ C,
    const float* __restrict__ attn,
    int* __restrict__ best,
    float* __restrict__ out)
{
    int bi = blockIdx.x;            // b*256 + (l for argmax, c for plane)
    int b  = bi >> 8;
    int t  = threadIdx.x;           // 0..255

    __shared__ float bmean[256];
    __shared__ float sval[256];
    __shared__ int   sidx[256];

    // Thread t owns 4x4 block t of plane bi: rows 4*(t>>4).., cols 4*(t&15)..
    // Per 16-lane group the 4 float4s cover one contiguous 256B row -> coalesced.
    const float* pbase = C + (size_t)bi * 4096 + ((t >> 4) * 4) * 64 + (t & 15) * 4;
    float4 r0 = *reinterpret_cast<const float4*>(pbase);
    float4 r1 = *reinterpret_cast<const float4*>(pbase + 64);
    float4 r2 = *reinterpret_cast<const float4*>(pbase + 128);
    float4 r3 = *reinterpret_cast<const float4*>(pbase + 192);

    // Argmax input: sum over heads of attn[b][h][l][j=t].
    const float* abase = attn + (((size_t)b * 8) * 256 + (bi & 255)) * 256;
    float s = 0.0f;
#pragma unroll
    for (int h = 0; h < 8; ++h)
        s += abase[(size_t)h * 65536 + t];

    bmean[t] = ((r0.x + r0.y) + (r0.z + r0.w) + (r1.x + r1.y) + (r1.z + r1.w) +
                (r2.x + r2.y) + (r2.z + r2.w) + (r3.x + r3.y) + (r3.z + r3.w)) *
               (1.0f / 16.0f);

    sval[t] = s;
    sidx[t] = t;
    __syncthreads();
#pragma unroll
    for (int off = 128; off > 0; off >>= 1) {
        if (t < off) {
            float v2 = sval[t + off];
            int   i2 = sidx[t + off];
            if (v2 > sval[t] || (v2 == sval[t] && i2 < sidx[t])) {
                sval[t] = v2;
                sidx[t] = i2;
            }
        }
        __syncthreads();
    }
    if (t == 0) best[bi] = sidx[0];

    cg::this_grid().sync();

    // Phase B: cell t of plane bi -> gather its selected block's mean.
    int   jstar = best[b * 256 + t];
    float v     = bmean[jstar];
    __syncthreads();                 // argmax use of sval done
    sval[t] = v;                     // reuse sval as cellavg
    __syncthreads();

    float4* out4 = reinterpret_cast<float4*>(out + (size_t)bi * 4096);
#pragma unroll
    for (int i = 0; i < 4; ++i) {
        int q4  = i * 1024 + t * 4;
        int row = q4 >> 6;
        int col = q4 & 63;
        float w = sval[(row >> 2) * 16 + (col >> 2)];
        out4[t + i * 256] = make_float4(w, w, w, w);
    }
}

// ---- Fallback path (proven round-1 kernels, 21 us) ----
__global__ void ca_argmax_kernel(const float* __restrict__ attn,
                                 int* __restrict__ best) {
    int bl = blockIdx.x;
    int b  = bl >> 8;
    int l  = bl & 255;
    int j  = threadIdx.x;

    const float* base = attn + (((size_t)b * 8) * 256 + l) * 256;
    float s = 0.0f;
#pragma unroll
    for (int h = 0; h < 8; ++h)
        s += base[(size_t)h * 65536 + j];

    __shared__ float sval[256];
    __shared__ int   sidx[256];
    sval[j] = s;
    sidx[j] = j;
    __syncthreads();
#pragma unroll
    for (int off = 128; off > 0; off >>= 1) {
        if (j < off) {
            float v2 = sval[j + off];
            int   i2 = sidx[j + off];
            if (v2 > sval[j] || (v2 == sval[j] && i2 < sidx[j])) {
                sval[j] = v2;
                sidx[j] = i2;
            }
        }
        __syncthreads();
    }
    if (j == 0) best[bl] = sidx[0];
}

__global__ void ca_resample_kernel(const float* __restrict__ C,
                                   const int* __restrict__ best,
                                   float* __restrict__ out) {
    int bc = blockIdx.x;
    int b  = bc >> 8;
    int t  = threadIdx.x;

    __shared__ float bmean[256];
    __shared__ float cellavg[256];

    const float* pbase = C + (size_t)bc * 4096 + ((t >> 4) * 4) * 64 + (t & 15) * 4;
    float4 r0 = *reinterpret_cast<const float4*>(pbase);
    float4 r1 = *reinterpret_cast<const float4*>(pbase + 64);
    float4 r2 = *reinterpret_cast<const float4*>(pbase + 128);
    float4 r3 = *reinterpret_cast<const float4*>(pbase + 192);
    bmean[t] = ((r0.x + r0.y) + (r0.z + r0.w) + (r1.x + r1.y) + (r1.z + r1.w) +
                (r2.x + r2.y) + (r2.z + r2.w) + (r3.x + r3.y) + (r3.z + r3.w)) *
               (1.0f / 16.0f);
    __syncthreads();

    cellavg[t] = bmean[best[b * 256 + t]];
    __syncthreads();

    float4* out4 = reinterpret_cast<float4*>(out + (size_t)bc * 4096);
#pragma unroll
    for (int i = 0; i < 4; ++i) {
        int q4  = i * 1024 + t * 4;
        int row = q4 >> 6;
        int col = q4 & 63;
        float v = cellavg[(row >> 2) * 16 + (col >> 2)];
        out4[t + i * 256] = make_float4(v, v, v, v);
    }
}

extern "C" void kernel_launch(void* const* d_in, const int* in_sizes, int n_in,
                              void* d_out, int out_size, void* d_ws, size_t ws_size,
                              hipStream_t stream) {
    const float* C    = (const float*)d_in[2];   // (8,256,64,64)
    const float* attn = (const float*)d_in[4];   // (8,8,256,256)
    float* out = (float*)d_out;
    int* best  = (int*)d_ws;                     // 2048 ints

    // Capture-safe host-side queries (no stream ops): decide path deterministically.
    int coop = 0, ncu = 0, blocksPerCU = 0;
    hipDeviceGetAttribute(&coop, hipDeviceAttributeCooperativeLaunch, 0);
    hipDeviceGetAttribute(&ncu, hipDeviceAttributeMultiprocessorCount, 0);
    hipOccupancyMaxActiveBlocksPerMultiprocessor(
        &blocksPerCU, reinterpret_cast<const void*>(ca_fused_kernel), 256, 0);

    bool coop_ok = false;
    if (coop && (long)blocksPerCU * ncu >= 2048) {
        void* args[] = { (void*)&C, (void*)&attn, (void*)&best, (void*)&out };
        hipError_t e = hipLaunchCooperativeKernel(
            reinterpret_cast<void*>(ca_fused_kernel),
            dim3(2048), dim3(256), args, 0, stream);
        coop_ok = (e == hipSuccess);
    }
    if (!coop_ok) {
        ca_argmax_kernel<<<2048, 256, 0, stream>>>(attn, best);
        ca_resample_kernel<<<2048, 256, 0, stream>>>(C, best, out);
    }
}